// Round 1
// baseline (624.863 us; speedup 1.0000x reference)
//
#include <hip/hip_runtime.h>
#include <hip/hip_fp16.h>

#define NN 64
#define HH 512
#define MM 64

// 1 WG = (node n, 64 batch rows). 512 threads = 8 waves; lane = batch row.
// Stage A: h1 = relu(xm . W1[n][h][:])      -> fp16 in LDS (xor-swizzled)
// Stage B: r1 partials per wave (half of h, 16 m's), reduced via LDS
// Stage C: h3 = relu(r1 . W3row + xn*W3[h][64+n] + b3), D: out += h3*W4[h]
// Weights are wave-uniform scalar loads (SGPR operand in FMA); activations in VGPRs.
__global__ __launch_bounds__(512, 2)
void causal_deriv_kernel(const float* __restrict__ x,
                         const float* __restrict__ W1,
                         const float* __restrict__ W2,
                         const float* __restrict__ W3,
                         const float* __restrict__ b3,
                         const float* __restrict__ W4,
                         const float* __restrict__ b4,
                         float* __restrict__ out)
{
    __shared__ __align__(16) float smem[16384];   // 64 KB

    const int tid = threadIdx.x;
    const int b   = tid & 63;                                   // lane = batch row in tile
    const int w   = __builtin_amdgcn_readfirstlane(tid >> 6);   // wave id 0..7 (uniform)

    const int bid  = blockIdx.x;            // 0..1023
    const int xcd  = bid & 7;               // XCD-locality: 8 nodes per XCD
    const int slot = bid >> 3;              // 0..127
    const int n    = (xcd << 3) + (slot >> 4);
    const int tile = slot & 15;
    const int bg   = (tile << 6) + b;       // global batch row

    // ---- load x row to registers; mask own element; capture own value ----
    float xm[NN];
    float xn = 0.f;
    {
        const float* xr = x + (bg << 6);
        #pragma unroll
        for (int i = 0; i < NN; i += 4) {
            float4 v = *(const float4*)(xr + i);
            xn = (i + 0 == n) ? v.x : xn;
            xn = (i + 1 == n) ? v.y : xn;
            xn = (i + 2 == n) ? v.z : xn;
            xn = (i + 3 == n) ? v.w : xn;
            xm[i + 0] = (i + 0 == n) ? 0.f : v.x;
            xm[i + 1] = (i + 1 == n) ? 0.f : v.y;
            xm[i + 2] = (i + 2 == n) ? 0.f : v.z;
            xm[i + 3] = (i + 3 == n) ? 0.f : v.w;
        }
    }

    __half2* h1h2 = (__half2*)smem;     // 64 rows x 256 half2, xor-swizzled columns
    const int swz = b & 31;             // 2 lanes/bank aliasing is free (m136)

    // ---- stage A: wave w computes h in [w*64, w*64+64) ----
    {
        const float* w1b = W1 + ((size_t)(n * HH) << 6);     // W1[n][h][i]
        for (int t = 0; t < 32; ++t) {                       // 2 h per iter
            const int h0 = (w << 6) + (t << 1);
            float r01[2];
            #pragma unroll
            for (int j = 0; j < 2; ++j) {
                const float* wr = w1b + ((h0 + j) << 6);     // uniform -> s_load
                float a0 = 0.f, a1 = 0.f, a2 = 0.f, a3 = 0.f;
                #pragma unroll
                for (int i = 0; i < NN; i += 4) {
                    a0 = fmaf(xm[i + 0], wr[i + 0], a0);
                    a1 = fmaf(xm[i + 1], wr[i + 1], a1);
                    a2 = fmaf(xm[i + 2], wr[i + 2], a2);
                    a3 = fmaf(xm[i + 3], wr[i + 3], a3);
                }
                r01[j] = fmaxf((a0 + a1) + (a2 + a3), 0.f);
            }
            const int e = h0 >> 1;                           // half2 column 0..255
            h1h2[(b << 8) + (e ^ swz)] = __floats2half2_rn(r01[0], r01[1]);
        }
    }
    __syncthreads();

    // ---- stage B: wave w -> h-half (w>>2), m-group (w&3): 16 partial r1 ----
    const int half = w >> 2;
    const int mg   = w & 3;
    float racc[16];
    #pragma unroll
    for (int m = 0; m < 16; ++m) racc[m] = 0.f;
    {
        const float* w2b = W2 + (size_t)(n * MM + (mg << 4)) * HH + (half << 8); // W2[n][m][h]
        #pragma unroll 4
        for (int cc = 0; cc < 128; ++cc) {                   // 2 h per iter over 256-h half
            const int e = (half << 7) + cc;
            float2 f = __half22float2(h1h2[(b << 8) + (e ^ swz)]);
            const int hoff = cc << 1;
            #pragma unroll
            for (int m = 0; m < 16; ++m) {
                const float* wr = w2b + m * HH + hoff;       // uniform -> s_load
                racc[m] = fmaf(f.x, wr[0], racc[m]);
                racc[m] = fmaf(f.y, wr[1], racc[m]);
            }
        }
    }
    __syncthreads();    // all h1 reads done; LDS reusable

    // ---- r1 partial store: [half][b][68] floats (float4 slots, stride 17) ----
    {
        float4* r4 = (float4*)smem;
        #pragma unroll
        for (int q = 0; q < 4; ++q) {
            r4[half * 1088 + b * 17 + (mg << 2) + q] =
                make_float4(racc[q * 4 + 0], racc[q * 4 + 1],
                            racc[q * 4 + 2], racc[q * 4 + 3]);
        }
    }
    __syncthreads();

    // ---- read back full r1 row, sum halves, relu ----
    float r1[MM];
    {
        const float4* r4 = (const float4*)smem;
        #pragma unroll
        for (int q = 0; q < 16; ++q) {
            float4 pa = r4[b * 17 + q];
            float4 pb = r4[1088 + b * 17 + q];
            r1[q * 4 + 0] = fmaxf(pa.x + pb.x, 0.f);
            r1[q * 4 + 1] = fmaxf(pa.y + pb.y, 0.f);
            r1[q * 4 + 2] = fmaxf(pa.z + pb.z, 0.f);
            r1[q * 4 + 3] = fmaxf(pa.w + pb.w, 0.f);
        }
    }

    // ---- stage C/D: wave w computes h in [w*64, w*64+64), accumulates out ----
    float oacc = 0.f;
    {
        const float* w3b = W3 + ((size_t)(n * HH) << 7);     // W3[n][h][k], k<128
        const float* b3p = b3 + n * HH;
        const float* w4p = W4 + n * HH;
        const int hend = (w << 6) + 64;
        #pragma unroll 2
        for (int h = (w << 6); h < hend; ++h) {
            const float* wr = w3b + (h << 7);                // uniform -> s_load
            float a0 = 0.f, a1 = 0.f, a2 = 0.f, a3 = 0.f;
            #pragma unroll
            for (int i = 0; i < MM; i += 4) {
                a0 = fmaf(r1[i + 0], wr[i + 0], a0);
                a1 = fmaf(r1[i + 1], wr[i + 1], a1);
                a2 = fmaf(r1[i + 2], wr[i + 2], a2);
                a3 = fmaf(r1[i + 3], wr[i + 3], a3);
            }
            float s = (a0 + a1) + (a2 + a3) + xn * wr[64 + n] + b3p[h];
            float h3 = fmaxf(s, 0.f);
            oacc = fmaf(h3, w4p[h], oacc);
        }
    }

    // ---- cross-wave reduction of out partials ----
    __syncthreads();    // r1 readback long done; LDS reusable
    smem[(w << 6) + b] = oacc;
    __syncthreads();
    if (w == 0) {
        float s = b4[n];
        #pragma unroll
        for (int k = 0; k < 8; ++k) s += smem[(k << 6) + b];
        out[(bg << 6) + n] = fmaxf(s, 0.f);
    }
}

extern "C" void kernel_launch(void* const* d_in, const int* in_sizes, int n_in,
                              void* d_out, int out_size, void* d_ws, size_t ws_size,
                              hipStream_t stream)
{
    const float* x  = (const float*)d_in[0];
    const float* W1 = (const float*)d_in[1];
    const float* W2 = (const float*)d_in[2];
    const float* W3 = (const float*)d_in[3];
    const float* b3 = (const float*)d_in[4];
    const float* W4 = (const float*)d_in[5];
    const float* b4 = (const float*)d_in[6];
    float* out = (float*)d_out;
    hipLaunchKernelGGL(causal_deriv_kernel, dim3(1024), dim3(512), 0, stream,
                       x, W1, W2, W3, b3, W4, b4, out);
}

// Round 2
// 221.070 us; speedup vs baseline: 2.8265x; 2.8265x over previous
//
#include <hip/hip_runtime.h>

#define NN 64
#define HH 512

typedef _Float16 h8 __attribute__((ext_vector_type(8)));
typedef float    fx4 __attribute__((ext_vector_type(4)));

// load 8 consecutive fp32, convert to an 8-half MFMA fragment
__device__ __forceinline__ h8 load_cvt_frag(const float* __restrict__ p) {
    float4 a = *(const float4*)p;
    float4 b = *(const float4*)(p + 4);
    h8 h;
    h[0] = (_Float16)a.x; h[1] = (_Float16)a.y; h[2] = (_Float16)a.z; h[3] = (_Float16)a.w;
    h[4] = (_Float16)b.x; h[5] = (_Float16)b.y; h[6] = (_Float16)b.z; h[7] = (_Float16)b.w;
    return h;
}

// 1 WG = (node n, 64 batch rows), 8 waves.
// A: H1 = relu(Xm @ W1^T)  — fused per-64h-chunk with
// B: r1 = relu(H1 @ W2^T)  — C2 accumulated in regs across chunks
// C: H3 = relu(r1 @ W3^T[:, :64] + xn*W3[:,64+n] + b3)
// D: out = relu(H3 . W4 + b4)  — butterfly-reduce over MFMA cols
// All GEMMs: v_mfma_f32_16x16x32_f16, fp32 accum. LDS rows padded to 72 halves.
__global__ __launch_bounds__(512, 4)
void causal_mfma_kernel(const float* __restrict__ x,
                        const float* __restrict__ W1,
                        const float* __restrict__ W2,
                        const float* __restrict__ W3,
                        const float* __restrict__ b3,
                        const float* __restrict__ W4,
                        const float* __restrict__ b4,
                        float* __restrict__ out)
{
    __shared__ __align__(16) char smem[39424];
    _Float16* XMh = (_Float16*)smem;          // [64][72] fp16, masked x tile
    _Float16* CH0 = XMh + 64 * 72;            // [2][64][72] fp16 h1 chunk (dbuf)
    _Float16* R1h = CH0 + 2 * 64 * 72;        // [64][72] fp16 r1
    float*    XNS = (float*)(smem + 36864);   // [64] fp32 x[b][n]
    float*    RED = XNS + 64;                 // [8][64] fp32 out partials

    const int tid  = threadIdx.x;
    const int bid  = blockIdx.x;
    const int n    = ((bid & 7) << 3) + ((bid >> 3) >> 4);  // XCD-local nodes
    const int tile = (bid >> 3) & 15;

    const int lane = tid & 63;
    const int pos  = lane & 15;
    const int quad = lane >> 4;
    const int wv   = __builtin_amdgcn_readfirstlane(tid >> 6);

    // ---- stage 0: x tile -> XM fp16 (own column zeroed), XNS ----
    {
        const int row = tid >> 3;
        const int c0  = (tid & 7) << 3;
        const float* xr = x + (((tile << 6) + row) << 6) + c0;
        float4 a = *(const float4*)xr, b = *(const float4*)(xr + 4);
        float v[8] = {a.x, a.y, a.z, a.w, b.x, b.y, b.z, b.w};
        #pragma unroll
        for (int j = 0; j < 8; ++j) if (c0 + j == n) v[j] = 0.f;
        h8 h;
        #pragma unroll
        for (int j = 0; j < 8; ++j) h[j] = (_Float16)v[j];
        *(h8*)(XMh + row * 72 + c0) = h;
        if (tid < 64) XNS[tid] = x[(((tile << 6) + tid) << 6) + n];
    }
    __syncthreads();

    // ---- A-fragments of Xm for this wave's M-tile (chunk-invariant) ----
    const int mtA = wv >> 1;            // M-tile (batch) 0..3
    const int ntA = (wv & 1) << 1;      // N-tile pair base 0 or 2
    h8 aX[2];
    #pragma unroll
    for (int ks = 0; ks < 2; ++ks)
        aX[ks] = *(const h8*)(XMh + (mtA * 16 + pos) * 72 + ks * 32 + quad * 8);

    const float* W1n = W1 + (size_t)n * HH * NN;
    const float* W2n = W2 + (size_t)n * NN * HH;

    // ---- fused stage A + B over 8 h-chunks ----
    fx4 acc2[2] = {};   // r1 tiles (rows=batch mtA*16.., cols=m (ntA+t)*16..)
    for (int c = 0; c < 8; ++c) {
        const int hb = c << 6;
        _Float16* CB = CH0 + (c & 1) * (64 * 72);
        // stage A: this wave's 2 tiles of the 64x64 h1 chunk
        #pragma unroll
        for (int t = 0; t < 2; ++t) {
            const int h = hb + (ntA + t) * 16 + pos;
            fx4 acc = {};
            #pragma unroll
            for (int ks = 0; ks < 2; ++ks) {
                h8 bf = load_cvt_frag(W1n + (size_t)h * NN + ks * 32 + quad * 8);
                acc = __builtin_amdgcn_mfma_f32_16x16x32_f16(aX[ks], bf, acc, 0, 0, 0);
            }
            #pragma unroll
            for (int r = 0; r < 4; ++r)
                CB[(mtA * 16 + quad * 4 + r) * 72 + (ntA + t) * 16 + pos] =
                    (_Float16)fmaxf(acc[r], 0.f);
        }
        __syncthreads();
        // stage B: accumulate C2 += H1chunk @ W2^T[chunk]
        h8 aH[2];
        #pragma unroll
        for (int ks = 0; ks < 2; ++ks)
            aH[ks] = *(const h8*)(CB + (mtA * 16 + pos) * 72 + ks * 32 + quad * 8);
        #pragma unroll
        for (int t = 0; t < 2; ++t) {
            const int m = (ntA + t) * 16 + pos;
            #pragma unroll
            for (int ks = 0; ks < 2; ++ks) {
                h8 bf = load_cvt_frag(W2n + (size_t)m * HH + hb + ks * 32 + quad * 8);
                acc2[t] = __builtin_amdgcn_mfma_f32_16x16x32_f16(aH[ks], bf, acc2[t], 0, 0, 0);
            }
        }
    }

    // ---- r1 -> LDS (fp16, A-operand layout) ----
    #pragma unroll
    for (int t = 0; t < 2; ++t)
        #pragma unroll
        for (int r = 0; r < 4; ++r)
            R1h[(mtA * 16 + quad * 4 + r) * 72 + (ntA + t) * 16 + pos] =
                (_Float16)fmaxf(acc2[t][r], 0.f);
    __syncthreads();

    // ---- stage C: H3 chunk (this wave: h in [wv*64, wv*64+64)) ----
    const int hc = wv << 6;
    const float* W3n = W3 + (size_t)n * HH * 128;
    fx4 acc3[4][4] = {};
    #pragma unroll
    for (int nt = 0; nt < 4; ++nt) {
        const int h = hc + nt * 16 + pos;
        #pragma unroll
        for (int ks = 0; ks < 2; ++ks) {
            h8 bf = load_cvt_frag(W3n + (size_t)h * 128 + ks * 32 + quad * 8);
            #pragma unroll
            for (int mt = 0; mt < 4; ++mt) {
                h8 af = *(const h8*)(R1h + (mt * 16 + pos) * 72 + ks * 32 + quad * 8);
                acc3[mt][nt] = __builtin_amdgcn_mfma_f32_16x16x32_f16(af, bf, acc3[mt][nt], 0, 0, 0);
            }
        }
    }

    // ---- fixup (+ xn*W3[:,64+n] + b3), relu, dot with W4 ----
    const int hP = hc + pos;
    float w3c[4], b3v[4], w4v[4];
    #pragma unroll
    for (int nt = 0; nt < 4; ++nt) {
        w3c[nt] = W3n[(size_t)(hP + nt * 16) * 128 + 64 + n];
        b3v[nt] = b3[n * HH + hP + nt * 16];
        w4v[nt] = W4[n * HH + hP + nt * 16];
    }
    float o[16];
    #pragma unroll
    for (int mt = 0; mt < 4; ++mt) {
        float4 xv = *(const float4*)(XNS + mt * 16 + quad * 4);
        float xvr[4] = {xv.x, xv.y, xv.z, xv.w};
        #pragma unroll
        for (int r = 0; r < 4; ++r) {
            float s = 0.f;
            #pragma unroll
            for (int nt = 0; nt < 4; ++nt) {
                float t = fmaxf(acc3[mt][nt][r] + fmaf(xvr[r], w3c[nt], b3v[nt]), 0.f);
                s = fmaf(t, w4v[nt], s);
            }
            o[mt * 4 + r] = s;
        }
    }

    // ---- butterfly-reduce over the 16 h-columns (pos lanes) ----
    #pragma unroll
    for (int m = 1; m < 16; m <<= 1)
        #pragma unroll
        for (int i = 0; i < 16; ++i)
            o[i] += __shfl_xor(o[i], m, 64);

    if (pos < 4) {
        #pragma unroll
        for (int mt = 0; mt < 4; ++mt)
            RED[wv * 64 + mt * 16 + quad * 4 + pos] = o[mt * 4 + pos];
    }
    __syncthreads();

    // ---- cross-wave sum + bias + relu + store ----
    if (tid < 64) {
        float s = b4[n];
        #pragma unroll
        for (int k = 0; k < 8; ++k) s += RED[k * 64 + tid];
        out[(((tile << 6) + tid) << 6) + n] = fmaxf(s, 0.f);
    }
}

extern "C" void kernel_launch(void* const* d_in, const int* in_sizes, int n_in,
                              void* d_out, int out_size, void* d_ws, size_t ws_size,
                              hipStream_t stream)
{
    const float* x  = (const float*)d_in[0];
    const float* W1 = (const float*)d_in[1];
    const float* W2 = (const float*)d_in[2];
    const float* W3 = (const float*)d_in[3];
    const float* b3 = (const float*)d_in[4];
    const float* W4 = (const float*)d_in[5];
    const float* b4 = (const float*)d_in[6];
    float* out = (float*)d_out;
    hipLaunchKernelGGL(causal_mfma_kernel, dim3(1024), dim3(512), 0, stream,
                       x, W1, W2, W3, b3, W4, b4, out);
}

// Round 3
// 111.168 us; speedup vs baseline: 5.6209x; 1.9886x over previous
//
#include <hip/hip_runtime.h>

#define NN 64
#define HH 512

typedef _Float16 h8 __attribute__((ext_vector_type(8)));
typedef float    fx4 __attribute__((ext_vector_type(4)));

#define MFMA __builtin_amdgcn_mfma_f32_16x16x32_f16

// cvt 16 fp32 (4 float4) -> 16 fp16 -> LDS (two h8 stores)
__device__ __forceinline__ void cvt_store16(_Float16* d, const float4* p) {
    h8 h0, h1;
    h0[0]=(_Float16)p[0].x; h0[1]=(_Float16)p[0].y; h0[2]=(_Float16)p[0].z; h0[3]=(_Float16)p[0].w;
    h0[4]=(_Float16)p[1].x; h0[5]=(_Float16)p[1].y; h0[6]=(_Float16)p[1].z; h0[7]=(_Float16)p[1].w;
    h1[0]=(_Float16)p[2].x; h1[1]=(_Float16)p[2].y; h1[2]=(_Float16)p[2].z; h1[3]=(_Float16)p[2].w;
    h1[4]=(_Float16)p[3].x; h1[5]=(_Float16)p[3].y; h1[6]=(_Float16)p[3].z; h1[7]=(_Float16)p[3].w;
    *(h8*)d = h0; *((h8*)d + 1) = h1;
}

// WG = 256 thr (4 waves), node n = bid&63, batch rows [tile*128, +128), wave owns 32 rows.
// Weights staged fp32->fp16 into dbuf LDS chunks (coalesced), MFMA 16x16x32_f16.
// Stage C folds xn*W3[:,64+n] + b3 into a 5th K-step MFMA.
__global__ __launch_bounds__(256, 2)
void causal_mfma3(const float* __restrict__ x,  const float* __restrict__ W1,
                  const float* __restrict__ W2, const float* __restrict__ W3,
                  const float* __restrict__ b3, const float* __restrict__ W4,
                  const float* __restrict__ b4, float* __restrict__ out)
{
    __shared__ __align__(16) char smem[61952];
    _Float16* W1c  = (_Float16*)smem;          // [2][64][72]  (stage C reuses as W3 dbuf)
    _Float16* W2c  = W1c + 2 * 4608;           // [2][64][72]
    _Float16* priv = W2c + 2 * 4608;           // [4 waves][32][72]
    float*    w3cs = (float*)(smem + 55296);   // [512]  W3[:,64+n]
    float*    b3s  = w3cs + 512;               // [512]
    float*    w4s  = b3s + 512;                // [512]
    float*    xns  = w4s + 512;                // [128]

    const int tid  = threadIdx.x;
    const int bid  = blockIdx.x;
    const int n    = bid & 63;                 // same-node WGs -> same bid%8 -> same XCD
    const int tile = bid >> 6;                 // 0..7
    const int lane = tid & 63;
    const int pos  = lane & 15;
    const int quad = lane >> 4;
    const int wv   = __builtin_amdgcn_readfirstlane(tid >> 6);   // 0..3
    const int row0 = tile * 128;
    const int wrow = wv << 5;                  // wave's 32-row base within WG

    const float* W1n = W1 + (size_t)n * HH * NN;
    const float* W2n = W2 + (size_t)n * NN * HH;
    const float* W3n = W3 + (size_t)n * HH * 128;

    const int trow = tid >> 2;                 // 0..63 (staging row)
    const int tcol = (tid & 3) << 4;           // 0,16,32,48

    // ---- prologue: chunk-0 weight staging + scalar arrays + xn + Xm A-frags ----
    {
        float4 p1[4], p2[4];
        #pragma unroll
        for (int q = 0; q < 4; ++q) p1[q] = *(const float4*)(W1n + trow * 64 + tcol + q * 4);
        #pragma unroll
        for (int q = 0; q < 4; ++q) p2[q] = *(const float4*)(W2n + (size_t)trow * HH + tcol + q * 4);
        #pragma unroll
        for (int k = 0; k < 2; ++k) {
            const int h = tid + k * 256;
            w3cs[h] = W3n[(size_t)h * 128 + 64 + n];
            b3s[h]  = b3[n * HH + h];
            w4s[h]  = W4[n * HH + h];
        }
        if (tid < 128) xns[tid] = x[(size_t)(row0 + tid) * NN + n];
        cvt_store16(W1c + trow * 72 + tcol, p1);
        cvt_store16(W2c + trow * 72 + tcol, p2);
    }

    // Xm A-fragments (own element zeroed) — chunk-invariant
    h8 aX[2][2];
    #pragma unroll
    for (int mt = 0; mt < 2; ++mt)
        #pragma unroll
        for (int ks = 0; ks < 2; ++ks) {
            const float* p = x + (size_t)(row0 + wrow + mt * 16 + pos) * NN + ks * 32 + quad * 8;
            float4 a = *(const float4*)p, bq = *(const float4*)(p + 4);
            float v[8] = {a.x, a.y, a.z, a.w, bq.x, bq.y, bq.z, bq.w};
            const int base = ks * 32 + quad * 8;
            #pragma unroll
            for (int j = 0; j < 8; ++j) if (base + j == n) v[j] = 0.f;
            h8 h;
            #pragma unroll
            for (int j = 0; j < 8; ++j) h[j] = (_Float16)v[j];
            aX[mt][ks] = h;
        }
    __syncthreads();

    _Float16* P = priv + wv * 2304;            // own 32x72 buffer

    // ---- fused stages A+B over 8 h-chunks of 64 ----
    fx4 acc2[2][4] = {};                       // r1: [mt][m-tile]
    for (int c = 0; c < 8; ++c) {
        const int cb = c & 1;
        float4 p1[4], p2[4];
        if (c < 7) {
            const int hb1 = (c + 1) << 6;
            #pragma unroll
            for (int q = 0; q < 4; ++q) p1[q] = *(const float4*)(W1n + (hb1 + trow) * 64 + tcol + q * 4);
            #pragma unroll
            for (int q = 0; q < 4; ++q) p2[q] = *(const float4*)(W2n + (size_t)trow * HH + hb1 + tcol + q * 4);
        }
        // stage A: h1 chunk = Xm @ W1chunk^T
        const _Float16* W1L = W1c + cb * 4608;
        fx4 accA[2][4] = {};
        #pragma unroll
        for (int ks = 0; ks < 2; ++ks)
            #pragma unroll
            for (int nt = 0; nt < 4; ++nt) {
                h8 bf = *(const h8*)(W1L + (nt * 16 + pos) * 72 + ks * 32 + quad * 8);
                accA[0][nt] = MFMA(aX[0][ks], bf, accA[0][nt], 0, 0, 0);
                accA[1][nt] = MFMA(aX[1][ks], bf, accA[1][nt], 0, 0, 0);
            }
        // h1 -> own LDS (relu, fp16), then A-frags for stage B
        #pragma unroll
        for (int mt = 0; mt < 2; ++mt)
            #pragma unroll
            for (int nt = 0; nt < 4; ++nt)
                #pragma unroll
                for (int r = 0; r < 4; ++r)
                    P[(mt * 16 + quad * 4 + r) * 72 + nt * 16 + pos] =
                        (_Float16)fmaxf(accA[mt][nt][r], 0.f);
        h8 aH[2][2];
        #pragma unroll
        for (int mt = 0; mt < 2; ++mt)
            #pragma unroll
            for (int ks = 0; ks < 2; ++ks)
                aH[mt][ks] = *(const h8*)(P + (mt * 16 + pos) * 72 + ks * 32 + quad * 8);
        // stage B: acc2 += h1chunk @ W2chunk^T
        const _Float16* W2L = W2c + cb * 4608;
        #pragma unroll
        for (int ks = 0; ks < 2; ++ks)
            #pragma unroll
            for (int cm = 0; cm < 4; ++cm) {
                h8 bf = *(const h8*)(W2L + (cm * 16 + pos) * 72 + ks * 32 + quad * 8);
                acc2[0][cm] = MFMA(aH[0][ks], bf, acc2[0][cm], 0, 0, 0);
                acc2[1][cm] = MFMA(aH[1][ks], bf, acc2[1][cm], 0, 0, 0);
            }
        if (c < 7) {
            cvt_store16(W1c + (cb ^ 1) * 4608 + trow * 72 + tcol, p1);
            cvt_store16(W2c + (cb ^ 1) * 4608 + trow * 72 + tcol, p2);
        }
        __syncthreads();
    }

    // ---- r1 -> own LDS (relu), read back as A-frags ----
    #pragma unroll
    for (int mt = 0; mt < 2; ++mt)
        #pragma unroll
        for (int cm = 0; cm < 4; ++cm)
            #pragma unroll
            for (int r = 0; r < 4; ++r)
                P[(mt * 16 + quad * 4 + r) * 72 + cm * 16 + pos] =
                    (_Float16)fmaxf(acc2[mt][cm][r], 0.f);
    h8 aR[2][2];
    #pragma unroll
    for (int mt = 0; mt < 2; ++mt)
        #pragma unroll
        for (int ks = 0; ks < 2; ++ks)
            aR[mt][ks] = *(const h8*)(P + (mt * 16 + pos) * 72 + ks * 32 + quad * 8);
    // fold A-frag: k=64 -> xn, k=65 -> 1 (only quad 0 lanes carry data)
    h8 af3[2];
    #pragma unroll
    for (int mt = 0; mt < 2; ++mt) {
        h8 h;
        #pragma unroll
        for (int j = 0; j < 8; ++j) h[j] = (_Float16)0.f;
        if (quad == 0) { h[0] = (_Float16)xns[wrow + mt * 16 + pos]; h[1] = (_Float16)1.f; }
        af3[mt] = h;
    }

    // ---- stage C/D over 8 h-chunks: W3 staged into W1c dbuf ----
    {
        float4 p3[4];
        #pragma unroll
        for (int q = 0; q < 4; ++q) p3[q] = *(const float4*)(W3n + (size_t)trow * 128 + tcol + q * 4);
        cvt_store16(W1c + trow * 72 + tcol, p3);
    }
    __syncthreads();

    float o[2][4] = {};
    for (int c = 0; c < 8; ++c) {
        const int cb = c & 1;
        const int hc = c << 6;
        float4 p3[4];
        if (c < 7) {
            #pragma unroll
            for (int q = 0; q < 4; ++q)
                p3[q] = *(const float4*)(W3n + (size_t)(hc + 64 + trow) * 128 + tcol + q * 4);
        }
        const _Float16* W3L = W1c + cb * 4608;
        fx4 acc3[2][4] = {};
        #pragma unroll
        for (int ks = 0; ks < 2; ++ks)
            #pragma unroll
            for (int nt = 0; nt < 4; ++nt) {
                h8 bf = *(const h8*)(W3L + (nt * 16 + pos) * 72 + ks * 32 + quad * 8);
                acc3[0][nt] = MFMA(aR[0][ks], bf, acc3[0][nt], 0, 0, 0);
                acc3[1][nt] = MFMA(aR[1][ks], bf, acc3[1][nt], 0, 0, 0);
            }
        // fold: += [xn,1] @ [w3c; b3]
        #pragma unroll
        for (int nt = 0; nt < 4; ++nt) {
            h8 bf3;
            #pragma unroll
            for (int j = 0; j < 8; ++j) bf3[j] = (_Float16)0.f;
            if (quad == 0) {
                const int h = hc + nt * 16 + pos;
                bf3[0] = (_Float16)w3cs[h];
                bf3[1] = (_Float16)b3s[h];
            }
            acc3[0][nt] = MFMA(af3[0], bf3, acc3[0][nt], 0, 0, 0);
            acc3[1][nt] = MFMA(af3[1], bf3, acc3[1][nt], 0, 0, 0);
        }
        // relu + W4 dot
        #pragma unroll
        for (int nt = 0; nt < 4; ++nt) {
            const float w4v = w4s[hc + nt * 16 + pos];
            #pragma unroll
            for (int mt = 0; mt < 2; ++mt)
                #pragma unroll
                for (int r = 0; r < 4; ++r)
                    o[mt][r] = fmaf(fmaxf(acc3[mt][nt][r], 0.f), w4v, o[mt][r]);
        }
        if (c < 7) cvt_store16(W1c + (cb ^ 1) * 4608 + trow * 72 + tcol, p3);
        __syncthreads();
    }

    // ---- reduce over the 16 h-columns (pos bits), store ----
    #pragma unroll
    for (int m = 1; m < 16; m <<= 1)
        #pragma unroll
        for (int mt = 0; mt < 2; ++mt)
            #pragma unroll
            for (int r = 0; r < 4; ++r)
                o[mt][r] += __shfl_xor(o[mt][r], m, 64);

    if (pos == 0) {
        const float bb = b4[n];
        #pragma unroll
        for (int mt = 0; mt < 2; ++mt)
            #pragma unroll
            for (int r = 0; r < 4; ++r) {
                const int row = row0 + wrow + mt * 16 + quad * 4 + r;
                out[(size_t)row * 64 + n] = fmaxf(o[mt][r] + bb, 0.f);
            }
    }
}

extern "C" void kernel_launch(void* const* d_in, const int* in_sizes, int n_in,
                              void* d_out, int out_size, void* d_ws, size_t ws_size,
                              hipStream_t stream)
{
    const float* x  = (const float*)d_in[0];
    const float* W1 = (const float*)d_in[1];
    const float* W2 = (const float*)d_in[2];
    const float* W3 = (const float*)d_in[3];
    const float* b3 = (const float*)d_in[4];
    const float* W4 = (const float*)d_in[5];
    const float* b4 = (const float*)d_in[6];
    float* out = (float*)d_out;
    hipLaunchKernelGGL(causal_mfma3, dim3(512), dim3(256), 0, stream,
                       x, W1, W2, W3, b3, W4, b4, out);
}